// Round 9
// baseline (53.307 us; speedup 1.0000x reference)
//
#include <hip/hip_runtime.h>

// UDTCWT split cascade, full-residency edition.
// K1: levels 1-4 (D=1,2,4,8), TS=2048, halo 68, padded double LDS, psi
//     transposed through dead LDS buffer -> coalesced float4 stores.
//     launch_bounds(256,8) -> 8 blocks/CU -> grid 2048 fully resident.
// K2: levels 5-8 (D=16..128), TS=4096, NT=512, SINGLE in-place PH-padded
//     LDS buffer (compute|bar|store pattern), launch_bounds(512,8)
//     -> 4 blocks/CU -> grid 1024 fully resident, zero tail.
// B=4, C=8 -> 16 chains, T=65536. Output: yl [4][8][T], yh [8][4][16][T].

static constexpr int B  = 4;
static constexpr int C2 = 16;
static constexpr int T  = 65536;

__device__ __forceinline__ float rfl(float x) {
    return __int_as_float(__builtin_amdgcn_readfirstlane(__float_as_int(x)));
}

__device__ __forceinline__ int PH(int p) { return p + (p >> 5); }

__device__ float g_phi4[(size_t)B * C2 * T]; // 16.8 MB phi-after-lvl4

// ---------------- K1 ----------------
static constexpr int NT1 = 256;
static constexpr int TS1 = 2048;
static constexpr int HB1 = 68;
static constexpr int S1  = TS1 + 2 * HB1;    // 2184
static constexpr int SP1 = S1 + S1 / 32;     // padded

template <int SH>
__device__ __forceinline__ void k1_lvl1(
    const float* __restrict__ in, float* __restrict__ out,
    const float* __restrict__ h0o, const float* __restrict__ h1o,
    float* __restrict__ psi_g, int gbase, int tid)
{
    float f0[5], f1[7];
#pragma unroll
    for (int k = 0; k < 5; ++k) f0[k] = rfl(h0o[k]);
#pragma unroll
    for (int k = 0; k < 7; ++k) f1[k] = rfl(h1o[k]);

    constexpr int WO    = SH ? -3 : -2;
    constexpr int FS    = SH ? 2 : 0;
    constexpr int MO    = 64;
    constexpr int START = HB1 - MO;        // 4
    constexpr int END   = HB1 + TS1 + MO;  // 2180

    for (int p4 = START + tid * 4; p4 < END; p4 += NT1 * 4) {
        float w[10];
#pragma unroll
        for (int k = 0; k < 10; ++k) w[k] = in[PH(p4 + WO + k)];
        float a[4];
#pragma unroll
        for (int i = 0; i < 4; ++i) {
            float s = 0.f;
#pragma unroll
            for (int k = 0; k < 5; ++k) s += w[i + k + FS] * f0[k];
            a[i] = s;
        }
        if ((unsigned)(p4 - HB1) < (unsigned)TS1) {
            float bb[4];
#pragma unroll
            for (int i = 0; i < 4; ++i) {
                float s = 0.f;
#pragma unroll
                for (int k = 0; k < 7; ++k) s += w[i + k] * f1[k];
                bb[i] = s;
            }
            *(float4*)&psi_g[gbase + p4] = make_float4(bb[0], bb[1], bb[2], bb[3]);
        }
        const bool inT = (unsigned)(gbase + p4) < (unsigned)T;
#pragma unroll
        for (int i = 0; i < 4; ++i) out[PH(p4 + i)] = inT ? a[i] : 0.f;
    }
}

// compute | bar | {phi->out, psi->in(stage)} | bar.  G<=NT1 single chunk.
template <int D, int W, int MO>
__device__ __forceinline__ void k1_level(
    float* __restrict__ in, float* __restrict__ out,
    const float (&f0)[10], const float (&f1)[10],
    int gbase, int tid)
{
    constexpr int HALF  = 9 * D / 2;
    constexpr int START = HB1 - MO;
    constexpr int N     = TS1 + 2 * MO;
    static_assert(N % D == 0, "");
    constexpr int NPD   = N / D;
    constexpr int CPC   = (NPD + W - 1) / W;
    constexpr int G     = D * CPC;
    static_assert(G <= NT1, "single chunk per thread required");
    constexpr int LOG2D = (D == 2 ? 1 : D == 4 ? 2 : 3);

    float a[W], bb[W];
    int p0 = 0;
    const bool act = tid < G;
    if (act) {
        int r  = tid & (D - 1);
        int q  = tid >> LOG2D;
        int ms = q * W;
        if (ms > NPD - W) ms = NPD - W;   // clamp (dup work, benign)
        p0 = START + r + ms * D;

        float v[W + 9];
#pragma unroll
        for (int n = 0; n < W + 9; ++n) v[n] = in[PH(p0 - HALF + n * D)];
#pragma unroll
        for (int m = 0; m < W; ++m) { a[m] = 0.f; bb[m] = 0.f; }
#pragma unroll
        for (int k = 0; k < 10; ++k)
#pragma unroll
            for (int m = 0; m < W; ++m) {
                float x = v[m + k];
                a[m] += x * f0[k]; bb[m] += x * f1[k];
            }
    }
    __syncthreads();
    if (act) {
#pragma unroll
        for (int m = 0; m < W; ++m) {
            int p = p0 + m * D;
            out[PH(p)] = ((unsigned)(gbase + p) < (unsigned)T) ? a[m] : 0.f;
            in[PH(p)]  = bb[m];
        }
    }
    __syncthreads();
}

__device__ __forceinline__ void k1_copyout(
    const float* __restrict__ buf, float* __restrict__ dst, int tid)
{
    for (int i4 = tid * 4; i4 < TS1; i4 += NT1 * 4) {
        int ph = PH(HB1 + i4);
        *(float4*)&dst[i4] = make_float4(buf[ph], buf[ph+1], buf[ph+2], buf[ph+3]);
    }
}

__global__ __launch_bounds__(256, 8) void udtcwt_k1(
    const float* __restrict__ x,
    const float* __restrict__ h0o, const float* __restrict__ h1o,
    const float* __restrict__ h0a, const float* __restrict__ h1a,
    const float* __restrict__ h0b, const float* __restrict__ h1b,
    float* __restrict__ out)
{
    __shared__ float A[SP1];
    __shared__ float Bf[SP1];

    const int tid   = threadIdx.x;
    const int bid   = blockIdx.x;
    const int tile  = bid & 31;
    const int chain = bid >> 5;
    const int shbit = chain & 1;
    const int cx    = (chain >> 1) & 7;
    const int b     = chain >> 4;
    const int c2    = shbit * 8 + cx;
    const int t0    = tile * TS1;
    const int gbase = t0 - HB1;          // %4 == 0

    const float* xin = x + (size_t)(b * 8 + cx) * T;
    for (int i4 = tid * 4; i4 < S1; i4 += NT1 * 4) {
        int gg = gbase + i4;
        float4 v = ((unsigned)gg < (unsigned)T)
                 ? *(const float4*)&xin[gg]
                 : make_float4(0.f, 0.f, 0.f, 0.f);
        int ph = PH(i4);
        A[ph] = v.x; A[ph+1] = v.y; A[ph+2] = v.z; A[ph+3] = v.w;
    }

    float f0[10], f1[10];
    {
        const float* F0 = (c2 & 1) ? h0b : h0a;
        const float* F1 = (c2 & 1) ? h1b : h1a;
#pragma unroll
        for (int k = 0; k < 10; ++k) { f0[k] = rfl(F0[k]); f1[k] = rfl(F1[k]); }
    }

    float* yh   = out + (size_t)B * 8 * T;
    const size_t LS = (size_t)B * C2 * T;
    float* psi0 = yh + (size_t)(b * C2 + c2) * T;

    __syncthreads();
    if (shbit) k1_lvl1<1>(A, Bf, h0o, h1o, psi0, gbase, tid);
    else       k1_lvl1<0>(A, Bf, h0o, h1o, psi0, gbase, tid);
    __syncthreads();

    k1_level<2, 9, 54>(Bf, A, f0, f1, gbase, tid);
    k1_copyout(Bf, psi0 + 1 * LS + t0, tid);
    k1_level<4, 9, 36>(A, Bf, f0, f1, gbase, tid);
    k1_copyout(A, psi0 + 2 * LS + t0, tid);
    k1_level<8, 9, 0>(Bf, A, f0, f1, gbase, tid);
    k1_copyout(Bf, psi0 + 3 * LS + t0, tid);
    k1_copyout(A, g_phi4 + (size_t)(b * C2 + c2) * T + t0, tid);
}

// ---------------- K2: levels 5-8, single in-place LDS buffer ----------------
static constexpr int NT2 = 512;
static constexpr int TS2 = 4096;
static constexpr int HB2 = 1080;
static constexpr int S2  = TS2 + 2 * HB2;    // 6256
static constexpr int SP2 = S2 + S2 / 32;     // 6451 padded (25.8 KB)

// In-place: all loads to regs before the barrier, stores after. Duplicate
// clamped chunks recompute identical values -> benign.
template <int D, int W, int MO, bool LAST>
__device__ __forceinline__ void k2_level(
    float* __restrict__ buf,
    const float (&f0)[10], const float (&f1)[10],
    float* __restrict__ psi_g, float* __restrict__ yl_g,
    int gbase, int tid, bool wr_yl)
{
    constexpr int HALF  = 9 * D / 2;
    constexpr int START = HB2 - MO;
    constexpr int N     = TS2 + 2 * MO;
    static_assert(N % D == 0, "");
    constexpr int NPD   = N / D;
    constexpr int CPC   = (NPD + W - 1) / W;
    constexpr int G     = D * CPC;
    static_assert(G <= NT2, "single chunk per thread required");
    constexpr int LOG2D = (D == 16 ? 4 : D == 32 ? 5 : D == 64 ? 6 : 7);

    float a[W], bb[W];
    int p0 = 0;
    const bool act = tid < G;
    if (act) {
        int r  = tid & (D - 1);
        int q  = tid >> LOG2D;
        int ms = q * W;
        if (ms > NPD - W) ms = NPD - W;
        p0 = START + r + ms * D;

        float v[W + 9];
#pragma unroll
        for (int n = 0; n < W + 9; ++n) v[n] = buf[PH(p0 - HALF + n * D)];
#pragma unroll
        for (int m = 0; m < W; ++m) { a[m] = 0.f; bb[m] = 0.f; }
#pragma unroll
        for (int k = 0; k < 10; ++k)
#pragma unroll
            for (int m = 0; m < W; ++m) {
                float x = v[m + k];
                a[m] += x * f0[k]; bb[m] += x * f1[k];
            }
    }
    __syncthreads();
    if (act) {
#pragma unroll
        for (int m = 0; m < W; ++m) {
            int p = p0 + m * D;
            const bool core = (unsigned)(p - HB2) < (unsigned)TS2;
            if (core) psi_g[gbase + p] = bb[m];
            if constexpr (!LAST) {
                buf[PH(p)] = ((unsigned)(gbase + p) < (unsigned)T) ? a[m] : 0.f;
            } else {
                if (wr_yl && core) yl_g[gbase + p] = a[m];
            }
        }
    }
    __syncthreads();
}

__global__ __launch_bounds__(512, 8) void udtcwt_k2(
    const float* __restrict__ h0a, const float* __restrict__ h1a,
    const float* __restrict__ h0b, const float* __restrict__ h1b,
    float* __restrict__ out)
{
    __shared__ float A[SP2];

    const int tid   = threadIdx.x;
    const int bid   = blockIdx.x;
    const int tile  = bid & 15;          // 16 tiles of 4096
    const int chain = bid >> 4;
    const int shbit = chain & 1;
    const int cx    = (chain >> 1) & 7;
    const int b     = chain >> 4;
    const int c2    = shbit * 8 + cx;
    const int gbase = tile * TS2 - HB2;  // %4 == 0

    const float* pin = g_phi4 + (size_t)(b * C2 + c2) * T;
    for (int i4 = tid * 4; i4 < S2; i4 += NT2 * 4) {
        int gg = gbase + i4;
        float4 v = ((unsigned)gg < (unsigned)T)
                 ? *(const float4*)&pin[gg]
                 : make_float4(0.f, 0.f, 0.f, 0.f);
        int ph = PH(i4);                 // quad phys-contiguous
        A[ph] = v.x; A[ph+1] = v.y; A[ph+2] = v.z; A[ph+3] = v.w;
    }

    float f0[10], f1[10];
    {
        const float* F0 = (c2 & 1) ? h0b : h0a;
        const float* F1 = (c2 & 1) ? h1b : h1a;
#pragma unroll
        for (int k = 0; k < 10; ++k) { f0[k] = rfl(F0[k]); f1[k] = rfl(F1[k]); }
    }

    float* yl_g = out + (size_t)(b * 8 + c2) * T;    // used when c2<8
    float* yh   = out + (size_t)B * 8 * T;
    const size_t LS = (size_t)B * C2 * T;
    float* psi0 = yh + (size_t)(b * C2 + c2) * T;
    const bool wr_yl = (c2 < 8);

    __syncthreads();
    k2_level< 16, 12, 1008, false>(A, f0, f1, psi0 + 4 * LS, nullptr, gbase, tid, false);
    k2_level< 32, 12,  864, false>(A, f0, f1, psi0 + 5 * LS, nullptr, gbase, tid, false);
    k2_level< 64, 12,  576, false>(A, f0, f1, psi0 + 6 * LS, nullptr, gbase, tid, false);
    k2_level<128,  9,    0, true >(A, f0, f1, psi0 + 7 * LS, yl_g,    gbase, tid, wr_yl);
}

extern "C" void kernel_launch(void* const* d_in, const int* in_sizes, int n_in,
                              void* d_out, int out_size, void* d_ws, size_t ws_size,
                              hipStream_t stream)
{
    const float* x   = (const float*)d_in[0];
    const float* h0o = (const float*)d_in[1];
    const float* h1o = (const float*)d_in[2];
    const float* h0a = (const float*)d_in[3];
    const float* h1a = (const float*)d_in[4];
    const float* h0b = (const float*)d_in[5];
    const float* h1b = (const float*)d_in[6];

    udtcwt_k1<<<64 * (T / TS1), NT1, 0, stream>>>(x, h0o, h1o, h0a, h1a, h0b, h1b,
                                                  (float*)d_out);
    udtcwt_k2<<<64 * (T / TS2), NT2, 0, stream>>>(h0a, h1a, h0b, h1b,
                                                  (float*)d_out);
}

// Round 10
// 53.166 us; speedup vs baseline: 1.0027x; 1.0027x over previous
//
#include <hip/hip_runtime.h>

// UDTCWT split cascade, r10 = r8-k1 + in-place-k2 without register squeeze.
// K1: levels 1-4 (D=1,2,4,8), TS=2048, halo 68, padded double LDS, psi
//     transposed through dead LDS buffer -> coalesced float4 stores.
//     LB(256,6): 85-VGPR budget (no spill), 6 blocks/CU.
// K2: levels 5-8 (D=16..128), TS=4096, NT=512, SINGLE in-place PH-padded
//     LDS buffer (compute|bar|store), LB(512,6): 85-VGPR budget; LDS 25.8KB
//     -> wave-capped 4 blocks/CU -> grid 1024 fully resident, zero tail.
// B=4, C=8 -> 16 chains, T=65536. Output: yl [4][8][T], yh [8][4][16][T].

static constexpr int B  = 4;
static constexpr int C2 = 16;
static constexpr int T  = 65536;

__device__ __forceinline__ float rfl(float x) {
    return __int_as_float(__builtin_amdgcn_readfirstlane(__float_as_int(x)));
}

__device__ __forceinline__ int PH(int p) { return p + (p >> 5); }

__device__ float g_phi4[(size_t)B * C2 * T]; // 16.8 MB phi-after-lvl4

// ---------------- K1 ----------------
static constexpr int NT1 = 256;
static constexpr int TS1 = 2048;
static constexpr int HB1 = 68;
static constexpr int S1  = TS1 + 2 * HB1;    // 2184
static constexpr int SP1 = S1 + S1 / 32;     // padded

template <int SH>
__device__ __forceinline__ void k1_lvl1(
    const float* __restrict__ in, float* __restrict__ out,
    const float* __restrict__ h0o, const float* __restrict__ h1o,
    float* __restrict__ psi_g, int gbase, int tid)
{
    float f0[5], f1[7];
#pragma unroll
    for (int k = 0; k < 5; ++k) f0[k] = rfl(h0o[k]);
#pragma unroll
    for (int k = 0; k < 7; ++k) f1[k] = rfl(h1o[k]);

    constexpr int WO    = SH ? -3 : -2;
    constexpr int FS    = SH ? 2 : 0;
    constexpr int MO    = 64;
    constexpr int START = HB1 - MO;        // 4
    constexpr int END   = HB1 + TS1 + MO;  // 2180

    for (int p4 = START + tid * 4; p4 < END; p4 += NT1 * 4) {
        float w[10];
#pragma unroll
        for (int k = 0; k < 10; ++k) w[k] = in[PH(p4 + WO + k)];
        float a[4];
#pragma unroll
        for (int i = 0; i < 4; ++i) {
            float s = 0.f;
#pragma unroll
            for (int k = 0; k < 5; ++k) s += w[i + k + FS] * f0[k];
            a[i] = s;
        }
        if ((unsigned)(p4 - HB1) < (unsigned)TS1) {
            float bb[4];
#pragma unroll
            for (int i = 0; i < 4; ++i) {
                float s = 0.f;
#pragma unroll
                for (int k = 0; k < 7; ++k) s += w[i + k] * f1[k];
                bb[i] = s;
            }
            *(float4*)&psi_g[gbase + p4] = make_float4(bb[0], bb[1], bb[2], bb[3]);
        }
        const bool inT = (unsigned)(gbase + p4) < (unsigned)T;
#pragma unroll
        for (int i = 0; i < 4; ++i) out[PH(p4 + i)] = inT ? a[i] : 0.f;
    }
}

// compute | bar | {phi->out, psi->in(stage)} | bar.  G<=NT1 single chunk.
template <int D, int W, int MO>
__device__ __forceinline__ void k1_level(
    float* __restrict__ in, float* __restrict__ out,
    const float (&f0)[10], const float (&f1)[10],
    int gbase, int tid)
{
    constexpr int HALF  = 9 * D / 2;
    constexpr int START = HB1 - MO;
    constexpr int N     = TS1 + 2 * MO;
    static_assert(N % D == 0, "");
    constexpr int NPD   = N / D;
    constexpr int CPC   = (NPD + W - 1) / W;
    constexpr int G     = D * CPC;
    static_assert(G <= NT1, "single chunk per thread required");
    constexpr int LOG2D = (D == 2 ? 1 : D == 4 ? 2 : 3);

    float a[W], bb[W];
    int p0 = 0;
    const bool act = tid < G;
    if (act) {
        int r  = tid & (D - 1);
        int q  = tid >> LOG2D;
        int ms = q * W;
        if (ms > NPD - W) ms = NPD - W;   // clamp (dup work, benign)
        p0 = START + r + ms * D;

        float v[W + 9];
#pragma unroll
        for (int n = 0; n < W + 9; ++n) v[n] = in[PH(p0 - HALF + n * D)];
#pragma unroll
        for (int m = 0; m < W; ++m) { a[m] = 0.f; bb[m] = 0.f; }
#pragma unroll
        for (int k = 0; k < 10; ++k)
#pragma unroll
            for (int m = 0; m < W; ++m) {
                float x = v[m + k];
                a[m] += x * f0[k]; bb[m] += x * f1[k];
            }
    }
    __syncthreads();
    if (act) {
#pragma unroll
        for (int m = 0; m < W; ++m) {
            int p = p0 + m * D;
            out[PH(p)] = ((unsigned)(gbase + p) < (unsigned)T) ? a[m] : 0.f;
            in[PH(p)]  = bb[m];
        }
    }
    __syncthreads();
}

__device__ __forceinline__ void k1_copyout(
    const float* __restrict__ buf, float* __restrict__ dst, int tid)
{
    for (int i4 = tid * 4; i4 < TS1; i4 += NT1 * 4) {
        int ph = PH(HB1 + i4);
        *(float4*)&dst[i4] = make_float4(buf[ph], buf[ph+1], buf[ph+2], buf[ph+3]);
    }
}

__global__ __launch_bounds__(256, 6) void udtcwt_k1(
    const float* __restrict__ x,
    const float* __restrict__ h0o, const float* __restrict__ h1o,
    const float* __restrict__ h0a, const float* __restrict__ h1a,
    const float* __restrict__ h0b, const float* __restrict__ h1b,
    float* __restrict__ out)
{
    __shared__ float A[SP1];
    __shared__ float Bf[SP1];

    const int tid   = threadIdx.x;
    const int bid   = blockIdx.x;
    const int tile  = bid & 31;
    const int chain = bid >> 5;
    const int shbit = chain & 1;
    const int cx    = (chain >> 1) & 7;
    const int b     = chain >> 4;
    const int c2    = shbit * 8 + cx;
    const int t0    = tile * TS1;
    const int gbase = t0 - HB1;          // %4 == 0

    const float* xin = x + (size_t)(b * 8 + cx) * T;
    for (int i4 = tid * 4; i4 < S1; i4 += NT1 * 4) {
        int gg = gbase + i4;
        float4 v = ((unsigned)gg < (unsigned)T)
                 ? *(const float4*)&xin[gg]
                 : make_float4(0.f, 0.f, 0.f, 0.f);
        int ph = PH(i4);
        A[ph] = v.x; A[ph+1] = v.y; A[ph+2] = v.z; A[ph+3] = v.w;
    }

    float f0[10], f1[10];
    {
        const float* F0 = (c2 & 1) ? h0b : h0a;
        const float* F1 = (c2 & 1) ? h1b : h1a;
#pragma unroll
        for (int k = 0; k < 10; ++k) { f0[k] = rfl(F0[k]); f1[k] = rfl(F1[k]); }
    }

    float* yh   = out + (size_t)B * 8 * T;
    const size_t LS = (size_t)B * C2 * T;
    float* psi0 = yh + (size_t)(b * C2 + c2) * T;

    __syncthreads();
    if (shbit) k1_lvl1<1>(A, Bf, h0o, h1o, psi0, gbase, tid);
    else       k1_lvl1<0>(A, Bf, h0o, h1o, psi0, gbase, tid);
    __syncthreads();

    k1_level<2, 9, 54>(Bf, A, f0, f1, gbase, tid);
    k1_copyout(Bf, psi0 + 1 * LS + t0, tid);
    k1_level<4, 9, 36>(A, Bf, f0, f1, gbase, tid);
    k1_copyout(A, psi0 + 2 * LS + t0, tid);
    k1_level<8, 9, 0>(Bf, A, f0, f1, gbase, tid);
    k1_copyout(Bf, psi0 + 3 * LS + t0, tid);
    k1_copyout(A, g_phi4 + (size_t)(b * C2 + c2) * T + t0, tid);
}

// ---------------- K2: levels 5-8, single in-place LDS buffer ----------------
static constexpr int NT2 = 512;
static constexpr int TS2 = 4096;
static constexpr int HB2 = 1080;
static constexpr int S2  = TS2 + 2 * HB2;    // 6256
static constexpr int SP2 = S2 + S2 / 32;     // padded (25.8 KB)

// In-place: all loads to regs before the barrier, stores after. Duplicate
// clamped chunks recompute identical values -> benign.
template <int D, int W, int MO, bool LAST>
__device__ __forceinline__ void k2_level(
    float* __restrict__ buf,
    const float (&f0)[10], const float (&f1)[10],
    float* __restrict__ psi_g, float* __restrict__ yl_g,
    int gbase, int tid, bool wr_yl)
{
    constexpr int HALF  = 9 * D / 2;
    constexpr int START = HB2 - MO;
    constexpr int N     = TS2 + 2 * MO;
    static_assert(N % D == 0, "");
    constexpr int NPD   = N / D;
    constexpr int CPC   = (NPD + W - 1) / W;
    constexpr int G     = D * CPC;
    static_assert(G <= NT2, "single chunk per thread required");
    constexpr int LOG2D = (D == 16 ? 4 : D == 32 ? 5 : D == 64 ? 6 : 7);

    float a[W], bb[W];
    int p0 = 0;
    const bool act = tid < G;
    const bool do_phi = !LAST || wr_yl;   // block-uniform
    if (act) {
        int r  = tid & (D - 1);
        int q  = tid >> LOG2D;
        int ms = q * W;
        if (ms > NPD - W) ms = NPD - W;
        p0 = START + r + ms * D;

        float v[W + 9];
#pragma unroll
        for (int n = 0; n < W + 9; ++n) v[n] = buf[PH(p0 - HALF + n * D)];
#pragma unroll
        for (int m = 0; m < W; ++m) { a[m] = 0.f; bb[m] = 0.f; }
        if (do_phi) {
#pragma unroll
            for (int k = 0; k < 10; ++k)
#pragma unroll
                for (int m = 0; m < W; ++m) {
                    float x = v[m + k];
                    a[m] += x * f0[k]; bb[m] += x * f1[k];
                }
        } else {
#pragma unroll
            for (int k = 0; k < 10; ++k)
#pragma unroll
                for (int m = 0; m < W; ++m) bb[m] += v[m + k] * f1[k];
        }
    }
    __syncthreads();
    if (act) {
#pragma unroll
        for (int m = 0; m < W; ++m) {
            int p = p0 + m * D;
            const bool core = (unsigned)(p - HB2) < (unsigned)TS2;
            if (core) psi_g[gbase + p] = bb[m];
            if constexpr (!LAST) {
                buf[PH(p)] = ((unsigned)(gbase + p) < (unsigned)T) ? a[m] : 0.f;
            } else {
                if (wr_yl && core) yl_g[gbase + p] = a[m];
            }
        }
    }
    __syncthreads();
}

__global__ __launch_bounds__(512, 6) void udtcwt_k2(
    const float* __restrict__ h0a, const float* __restrict__ h1a,
    const float* __restrict__ h0b, const float* __restrict__ h1b,
    float* __restrict__ out)
{
    __shared__ float A[SP2];

    const int tid   = threadIdx.x;
    const int bid   = blockIdx.x;
    const int tile  = bid & 15;          // 16 tiles of 4096
    const int chain = bid >> 4;
    const int shbit = chain & 1;
    const int cx    = (chain >> 1) & 7;
    const int b     = chain >> 4;
    const int c2    = shbit * 8 + cx;
    const int gbase = tile * TS2 - HB2;  // %4 == 0

    const float* pin = g_phi4 + (size_t)(b * C2 + c2) * T;
    for (int i4 = tid * 4; i4 < S2; i4 += NT2 * 4) {
        int gg = gbase + i4;
        float4 v = ((unsigned)gg < (unsigned)T)
                 ? *(const float4*)&pin[gg]
                 : make_float4(0.f, 0.f, 0.f, 0.f);
        int ph = PH(i4);                 // quad phys-contiguous
        A[ph] = v.x; A[ph+1] = v.y; A[ph+2] = v.z; A[ph+3] = v.w;
    }

    float f0[10], f1[10];
    {
        const float* F0 = (c2 & 1) ? h0b : h0a;
        const float* F1 = (c2 & 1) ? h1b : h1a;
#pragma unroll
        for (int k = 0; k < 10; ++k) { f0[k] = rfl(F0[k]); f1[k] = rfl(F1[k]); }
    }

    float* yl_g = out + (size_t)(b * 8 + c2) * T;    // used when c2<8
    float* yh   = out + (size_t)B * 8 * T;
    const size_t LS = (size_t)B * C2 * T;
    float* psi0 = yh + (size_t)(b * C2 + c2) * T;
    const bool wr_yl = (c2 < 8);

    __syncthreads();
    k2_level< 16, 12, 1008, false>(A, f0, f1, psi0 + 4 * LS, nullptr, gbase, tid, false);
    k2_level< 32, 12,  864, false>(A, f0, f1, psi0 + 5 * LS, nullptr, gbase, tid, false);
    k2_level< 64, 12,  576, false>(A, f0, f1, psi0 + 6 * LS, nullptr, gbase, tid, false);
    k2_level<128,  9,    0, true >(A, f0, f1, psi0 + 7 * LS, yl_g,    gbase, tid, wr_yl);
}

extern "C" void kernel_launch(void* const* d_in, const int* in_sizes, int n_in,
                              void* d_out, int out_size, void* d_ws, size_t ws_size,
                              hipStream_t stream)
{
    const float* x   = (const float*)d_in[0];
    const float* h0o = (const float*)d_in[1];
    const float* h1o = (const float*)d_in[2];
    const float* h0a = (const float*)d_in[3];
    const float* h1a = (const float*)d_in[4];
    const float* h0b = (const float*)d_in[5];
    const float* h1b = (const float*)d_in[6];

    udtcwt_k1<<<64 * (T / TS1), NT1, 0, stream>>>(x, h0o, h1o, h0a, h1a, h0b, h1b,
                                                  (float*)d_out);
    udtcwt_k2<<<64 * (T / TS2), NT2, 0, stream>>>(h0a, h1a, h0b, h1b,
                                                  (float*)d_out);
}

// Round 11
// 50.447 us; speedup vs baseline: 1.0567x; 1.0539x over previous
//
#include <hip/hip_runtime.h>

// UDTCWT split cascade = round-8 50.4us config + LDS-only barriers.
// Every __syncthreads() -> {s_waitcnt lgkmcnt(0); s_barrier}: global psi
// stores stay in flight across barriers (disjoint addresses; end-of-kernel
// drain guarantees completion before harness validation).
// K1: levels 1-4 (D=1,2,4,8), TS=2048, halo 68, padded double LDS, psi
//     transposed through dead LDS buffer -> coalesced float4 stores.
// K2: levels 5-8 (D=16..128), TS=4096, NT=512, double LDS, polyphase W=9.
// B=4, C=8 -> 16 chains, T=65536. Output: yl [4][8][T], yh [8][4][16][T].

static constexpr int B  = 4;
static constexpr int C2 = 16;
static constexpr int T  = 65536;

__device__ __forceinline__ float rfl(float x) {
    return __int_as_float(__builtin_amdgcn_readfirstlane(__float_as_int(x)));
}

__device__ __forceinline__ int PH(int p) { return p + (p >> 5); }

// LDS-only barrier: do NOT drain vmcnt (global stores keep flying).
__device__ __forceinline__ void bar_lds() {
    asm volatile("s_waitcnt lgkmcnt(0)" ::: "memory");
    __builtin_amdgcn_s_barrier();
}

__device__ float g_phi4[(size_t)B * C2 * T]; // 16.8 MB phi-after-lvl4

// ---------------- K1 ----------------
static constexpr int NT1 = 256;
static constexpr int TS1 = 2048;
static constexpr int HB1 = 68;
static constexpr int S1  = TS1 + 2 * HB1;    // 2184
static constexpr int SP1 = S1 + S1 / 32;     // padded

template <int SH>
__device__ __forceinline__ void k1_lvl1(
    const float* __restrict__ in, float* __restrict__ out,
    const float* __restrict__ h0o, const float* __restrict__ h1o,
    float* __restrict__ psi_g, int gbase, int tid)
{
    float f0[5], f1[7];
#pragma unroll
    for (int k = 0; k < 5; ++k) f0[k] = rfl(h0o[k]);
#pragma unroll
    for (int k = 0; k < 7; ++k) f1[k] = rfl(h1o[k]);

    constexpr int WO    = SH ? -3 : -2;
    constexpr int FS    = SH ? 2 : 0;
    constexpr int MO    = 64;
    constexpr int START = HB1 - MO;        // 4
    constexpr int END   = HB1 + TS1 + MO;  // 2180

    for (int p4 = START + tid * 4; p4 < END; p4 += NT1 * 4) {
        float w[10];
#pragma unroll
        for (int k = 0; k < 10; ++k) w[k] = in[PH(p4 + WO + k)];
        float a[4];
#pragma unroll
        for (int i = 0; i < 4; ++i) {
            float s = 0.f;
#pragma unroll
            for (int k = 0; k < 5; ++k) s += w[i + k + FS] * f0[k];
            a[i] = s;
        }
        if ((unsigned)(p4 - HB1) < (unsigned)TS1) {
            float bb[4];
#pragma unroll
            for (int i = 0; i < 4; ++i) {
                float s = 0.f;
#pragma unroll
                for (int k = 0; k < 7; ++k) s += w[i + k] * f1[k];
                bb[i] = s;
            }
            *(float4*)&psi_g[gbase + p4] = make_float4(bb[0], bb[1], bb[2], bb[3]);
        }
        const bool inT = (unsigned)(gbase + p4) < (unsigned)T;
#pragma unroll
        for (int i = 0; i < 4; ++i) out[PH(p4 + i)] = inT ? a[i] : 0.f;
    }
}

// compute | bar | {phi->out, psi->in(stage)} | bar.  G<=NT1 single chunk.
template <int D, int W, int MO>
__device__ __forceinline__ void k1_level(
    float* __restrict__ in, float* __restrict__ out,
    const float (&f0)[10], const float (&f1)[10],
    int gbase, int tid)
{
    constexpr int HALF  = 9 * D / 2;
    constexpr int START = HB1 - MO;
    constexpr int N     = TS1 + 2 * MO;
    static_assert(N % D == 0, "");
    constexpr int NPD   = N / D;
    constexpr int CPC   = (NPD + W - 1) / W;
    constexpr int G     = D * CPC;
    static_assert(G <= NT1, "single chunk per thread required");
    constexpr int LOG2D = (D == 2 ? 1 : D == 4 ? 2 : 3);

    float a[W], bb[W];
    int p0 = 0;
    const bool act = tid < G;
    if (act) {
        int r  = tid & (D - 1);
        int q  = tid >> LOG2D;
        int ms = q * W;
        if (ms > NPD - W) ms = NPD - W;   // clamp (dup work, benign)
        p0 = START + r + ms * D;

        float v[W + 9];
#pragma unroll
        for (int n = 0; n < W + 9; ++n) v[n] = in[PH(p0 - HALF + n * D)];
#pragma unroll
        for (int m = 0; m < W; ++m) { a[m] = 0.f; bb[m] = 0.f; }
#pragma unroll
        for (int k = 0; k < 10; ++k)
#pragma unroll
            for (int m = 0; m < W; ++m) {
                float x = v[m + k];
                a[m] += x * f0[k]; bb[m] += x * f1[k];
            }
    }
    bar_lds();
    if (act) {
#pragma unroll
        for (int m = 0; m < W; ++m) {
            int p = p0 + m * D;
            out[PH(p)] = ((unsigned)(gbase + p) < (unsigned)T) ? a[m] : 0.f;
            in[PH(p)]  = bb[m];
        }
    }
    bar_lds();
}

__device__ __forceinline__ void k1_copyout(
    const float* __restrict__ buf, float* __restrict__ dst, int tid)
{
    for (int i4 = tid * 4; i4 < TS1; i4 += NT1 * 4) {
        int ph = PH(HB1 + i4);
        *(float4*)&dst[i4] = make_float4(buf[ph], buf[ph+1], buf[ph+2], buf[ph+3]);
    }
}

__global__ __launch_bounds__(256, 6) void udtcwt_k1(
    const float* __restrict__ x,
    const float* __restrict__ h0o, const float* __restrict__ h1o,
    const float* __restrict__ h0a, const float* __restrict__ h1a,
    const float* __restrict__ h0b, const float* __restrict__ h1b,
    float* __restrict__ out)
{
    __shared__ float A[SP1];
    __shared__ float Bf[SP1];

    const int tid   = threadIdx.x;
    const int bid   = blockIdx.x;
    const int tile  = bid & 31;
    const int chain = bid >> 5;
    const int shbit = chain & 1;
    const int cx    = (chain >> 1) & 7;
    const int b     = chain >> 4;
    const int c2    = shbit * 8 + cx;
    const int t0    = tile * TS1;
    const int gbase = t0 - HB1;          // %4 == 0

    const float* xin = x + (size_t)(b * 8 + cx) * T;
    for (int i4 = tid * 4; i4 < S1; i4 += NT1 * 4) {
        int gg = gbase + i4;
        float4 v = ((unsigned)gg < (unsigned)T)
                 ? *(const float4*)&xin[gg]
                 : make_float4(0.f, 0.f, 0.f, 0.f);
        int ph = PH(i4);
        A[ph] = v.x; A[ph+1] = v.y; A[ph+2] = v.z; A[ph+3] = v.w;
    }

    float f0[10], f1[10];
    {
        const float* F0 = (c2 & 1) ? h0b : h0a;
        const float* F1 = (c2 & 1) ? h1b : h1a;
#pragma unroll
        for (int k = 0; k < 10; ++k) { f0[k] = rfl(F0[k]); f1[k] = rfl(F1[k]); }
    }

    float* yh   = out + (size_t)B * 8 * T;
    const size_t LS = (size_t)B * C2 * T;
    float* psi0 = yh + (size_t)(b * C2 + c2) * T;

    bar_lds();
    if (shbit) k1_lvl1<1>(A, Bf, h0o, h1o, psi0, gbase, tid);
    else       k1_lvl1<0>(A, Bf, h0o, h1o, psi0, gbase, tid);
    bar_lds();

    k1_level<2, 9, 54>(Bf, A, f0, f1, gbase, tid);
    k1_copyout(Bf, psi0 + 1 * LS + t0, tid);
    k1_level<4, 9, 36>(A, Bf, f0, f1, gbase, tid);
    k1_copyout(A, psi0 + 2 * LS + t0, tid);
    k1_level<8, 9, 0>(Bf, A, f0, f1, gbase, tid);
    k1_copyout(Bf, psi0 + 3 * LS + t0, tid);
    k1_copyout(A, g_phi4 + (size_t)(b * C2 + c2) * T + t0, tid);
}

// ---------------- K2: levels 5-8, double buffer, NT=512 ----------------
static constexpr int NT2 = 512;
static constexpr int TS2 = 4096;
static constexpr int HB2 = 1080;
static constexpr int S2  = TS2 + 2 * HB2;    // 6256

template <int D, int MO, bool LAST>
__device__ __forceinline__ void k2_poly(
    const float* __restrict__ in, float* __restrict__ out,
    const float (&f0)[10], const float (&f1)[10],
    float* __restrict__ psi_g, float* __restrict__ yl_g,
    int gbase, int tid, bool wr_yl)
{
    constexpr int W     = 9;
    constexpr int HALF  = 9 * D / 2;
    constexpr int START = HB2 - MO;
    constexpr int END   = HB2 + TS2 + MO;
    constexpr int N     = END - START;
    static_assert(N % D == 0, "");
    constexpr int NPD   = N / D;
    constexpr int CPC   = (NPD + W - 1) / W;
    constexpr int G     = D * CPC;
    constexpr int LOG2D = (D == 16 ? 4 : D == 32 ? 5 : D == 64 ? 6 : 7);

    for (int g = tid; g < G; g += NT2) {
        int r = g & (D - 1);
        int q = g >> LOG2D;
        int ms = q * W;
        if (ms > NPD - W) ms = NPD - W;
        int p0 = START + r + ms * D;

        float v[W + 9];
#pragma unroll
        for (int n = 0; n < W + 9; ++n) v[n] = in[p0 - HALF + n * D];

        if constexpr (!LAST) {
            const bool anyc = (p0 + (W - 1) * D >= HB2) && (p0 < HB2 + TS2);
            float a[W], bb[W];
            if (anyc) {
#pragma unroll
                for (int m = 0; m < W; ++m) { a[m] = 0.f; bb[m] = 0.f; }
#pragma unroll
                for (int k = 0; k < 10; ++k)
#pragma unroll
                    for (int m = 0; m < W; ++m) {
                        float xx = v[m + k];
                        a[m] += xx * f0[k]; bb[m] += xx * f1[k];
                    }
#pragma unroll
                for (int m = 0; m < W; ++m) {
                    int p = p0 + m * D;
                    if ((unsigned)(p - HB2) < (unsigned)TS2)
                        psi_g[gbase + p] = bb[m];
                }
            } else {
#pragma unroll
                for (int m = 0; m < W; ++m) a[m] = 0.f;
#pragma unroll
                for (int k = 0; k < 10; ++k)
#pragma unroll
                    for (int m = 0; m < W; ++m) a[m] += v[m + k] * f0[k];
            }
#pragma unroll
            for (int m = 0; m < W; ++m) {
                int p = p0 + m * D;
                out[p] = ((unsigned)(gbase + p) < (unsigned)T) ? a[m] : 0.f;
            }
        } else {
            float bb[W];
#pragma unroll
            for (int m = 0; m < W; ++m) bb[m] = 0.f;
#pragma unroll
            for (int k = 0; k < 10; ++k)
#pragma unroll
                for (int m = 0; m < W; ++m) bb[m] += v[m + k] * f1[k];
#pragma unroll
            for (int m = 0; m < W; ++m) psi_g[gbase + p0 + m * D] = bb[m];
            if (wr_yl) {
                float a[W];
#pragma unroll
                for (int m = 0; m < W; ++m) a[m] = 0.f;
#pragma unroll
                for (int k = 0; k < 10; ++k)
#pragma unroll
                    for (int m = 0; m < W; ++m) a[m] += v[m + k] * f0[k];
#pragma unroll
                for (int m = 0; m < W; ++m) yl_g[gbase + p0 + m * D] = a[m];
            }
        }
    }
}

__global__ __launch_bounds__(512, 6) void udtcwt_k2(
    const float* __restrict__ h0a, const float* __restrict__ h1a,
    const float* __restrict__ h0b, const float* __restrict__ h1b,
    float* __restrict__ out)
{
    __shared__ float A[S2];
    __shared__ float Bf[S2];

    const int tid   = threadIdx.x;
    const int bid   = blockIdx.x;
    const int tile  = bid & 15;          // 16 tiles of 4096
    const int chain = bid >> 4;
    const int shbit = chain & 1;
    const int cx    = (chain >> 1) & 7;
    const int b     = chain >> 4;
    const int c2    = shbit * 8 + cx;
    const int gbase = tile * TS2 - HB2;  // %4 == 0

    const float* pin = g_phi4 + (size_t)(b * C2 + c2) * T;
    for (int i4 = tid * 4; i4 < S2; i4 += NT2 * 4) {
        int gg = gbase + i4;
        float4 v = ((unsigned)gg < (unsigned)T)
                 ? *(const float4*)&pin[gg]
                 : make_float4(0.f, 0.f, 0.f, 0.f);
        *(float4*)&A[i4] = v;
    }

    float f0[10], f1[10];
    {
        const float* F0 = (c2 & 1) ? h0b : h0a;
        const float* F1 = (c2 & 1) ? h1b : h1a;
#pragma unroll
        for (int k = 0; k < 10; ++k) { f0[k] = rfl(F0[k]); f1[k] = rfl(F1[k]); }
    }

    float* yl_g = out + (size_t)(b * 8 + c2) * T;    // used when c2<8
    float* yh   = out + (size_t)B * 8 * T;
    const size_t LS = (size_t)B * C2 * T;
    float* psi0 = yh + (size_t)(b * C2 + c2) * T;
    const bool wr_yl = (c2 < 8);

    bar_lds();
    k2_poly<16, 1008, false>(A, Bf, f0, f1, psi0 + 4 * LS, nullptr, gbase, tid, false);
    bar_lds();
    k2_poly<32,  864, false>(Bf, A, f0, f1, psi0 + 5 * LS, nullptr, gbase, tid, false);
    bar_lds();
    k2_poly<64,  576, false>(A, Bf, f0, f1, psi0 + 6 * LS, nullptr, gbase, tid, false);
    bar_lds();
    k2_poly<128,   0, true >(Bf, A, f0, f1, psi0 + 7 * LS, yl_g, gbase, tid, wr_yl);
}

extern "C" void kernel_launch(void* const* d_in, const int* in_sizes, int n_in,
                              void* d_out, int out_size, void* d_ws, size_t ws_size,
                              hipStream_t stream)
{
    const float* x   = (const float*)d_in[0];
    const float* h0o = (const float*)d_in[1];
    const float* h1o = (const float*)d_in[2];
    const float* h0a = (const float*)d_in[3];
    const float* h1a = (const float*)d_in[4];
    const float* h0b = (const float*)d_in[5];
    const float* h1b = (const float*)d_in[6];

    udtcwt_k1<<<64 * (T / TS1), NT1, 0, stream>>>(x, h0o, h1o, h0a, h1a, h0b, h1b,
                                                  (float*)d_out);
    udtcwt_k2<<<64 * (T / TS2), NT2, 0, stream>>>(h0a, h1a, h0b, h1b,
                                                  (float*)d_out);
}

// Round 12
// 48.978 us; speedup vs baseline: 1.0884x; 1.0300x over previous
//
#include <hip/hip_runtime.h>

// UDTCWT split cascade. r12 = r11-k1 (proven 50.4) + big-tile in-place k2.
// K1: levels 1-4 (D=1,2,4,8), TS=2048, halo 68, padded double LDS, psi
//     transposed through dead LDS buffer -> coalesced float4 stores.
// K2: levels 5-8 (D=16..128), TS=8192, NT=768, W=15, SINGLE in-place
//     unpadded LDS buffer (compute|bar|store), 41.4KB -> 2 blocks/CU,
//     grid 512 fully resident zero-tail, all levels single-pass (G<=768).
// B=4, C=8 -> 16 chains, T=65536. Output: yl [4][8][T], yh [8][4][16][T].

static constexpr int B  = 4;
static constexpr int C2 = 16;
static constexpr int T  = 65536;

__device__ __forceinline__ float rfl(float x) {
    return __int_as_float(__builtin_amdgcn_readfirstlane(__float_as_int(x)));
}

__device__ __forceinline__ int PH(int p) { return p + (p >> 5); }

// LDS-only barrier (neutral vs __syncthreads, measured r11; keeps stores in flight)
__device__ __forceinline__ void bar_lds() {
    asm volatile("s_waitcnt lgkmcnt(0)" ::: "memory");
    __builtin_amdgcn_s_barrier();
}

__device__ float g_phi4[(size_t)B * C2 * T]; // 16.8 MB phi-after-lvl4

// ---------------- K1 (unchanged from r11 / r8) ----------------
static constexpr int NT1 = 256;
static constexpr int TS1 = 2048;
static constexpr int HB1 = 68;
static constexpr int S1  = TS1 + 2 * HB1;    // 2184
static constexpr int SP1 = S1 + S1 / 32;     // padded

template <int SH>
__device__ __forceinline__ void k1_lvl1(
    const float* __restrict__ in, float* __restrict__ out,
    const float* __restrict__ h0o, const float* __restrict__ h1o,
    float* __restrict__ psi_g, int gbase, int tid)
{
    float f0[5], f1[7];
#pragma unroll
    for (int k = 0; k < 5; ++k) f0[k] = rfl(h0o[k]);
#pragma unroll
    for (int k = 0; k < 7; ++k) f1[k] = rfl(h1o[k]);

    constexpr int WO    = SH ? -3 : -2;
    constexpr int FS    = SH ? 2 : 0;
    constexpr int MO    = 64;
    constexpr int START = HB1 - MO;        // 4
    constexpr int END   = HB1 + TS1 + MO;  // 2180

    for (int p4 = START + tid * 4; p4 < END; p4 += NT1 * 4) {
        float w[10];
#pragma unroll
        for (int k = 0; k < 10; ++k) w[k] = in[PH(p4 + WO + k)];
        float a[4];
#pragma unroll
        for (int i = 0; i < 4; ++i) {
            float s = 0.f;
#pragma unroll
            for (int k = 0; k < 5; ++k) s += w[i + k + FS] * f0[k];
            a[i] = s;
        }
        if ((unsigned)(p4 - HB1) < (unsigned)TS1) {
            float bb[4];
#pragma unroll
            for (int i = 0; i < 4; ++i) {
                float s = 0.f;
#pragma unroll
                for (int k = 0; k < 7; ++k) s += w[i + k] * f1[k];
                bb[i] = s;
            }
            *(float4*)&psi_g[gbase + p4] = make_float4(bb[0], bb[1], bb[2], bb[3]);
        }
        const bool inT = (unsigned)(gbase + p4) < (unsigned)T;
#pragma unroll
        for (int i = 0; i < 4; ++i) out[PH(p4 + i)] = inT ? a[i] : 0.f;
    }
}

template <int D, int W, int MO>
__device__ __forceinline__ void k1_level(
    float* __restrict__ in, float* __restrict__ out,
    const float (&f0)[10], const float (&f1)[10],
    int gbase, int tid)
{
    constexpr int HALF  = 9 * D / 2;
    constexpr int START = HB1 - MO;
    constexpr int N     = TS1 + 2 * MO;
    static_assert(N % D == 0, "");
    constexpr int NPD   = N / D;
    constexpr int CPC   = (NPD + W - 1) / W;
    constexpr int G     = D * CPC;
    static_assert(G <= NT1, "single chunk per thread required");
    constexpr int LOG2D = (D == 2 ? 1 : D == 4 ? 2 : 3);

    float a[W], bb[W];
    int p0 = 0;
    const bool act = tid < G;
    if (act) {
        int r  = tid & (D - 1);
        int q  = tid >> LOG2D;
        int ms = q * W;
        if (ms > NPD - W) ms = NPD - W;   // clamp (dup work, benign)
        p0 = START + r + ms * D;

        float v[W + 9];
#pragma unroll
        for (int n = 0; n < W + 9; ++n) v[n] = in[PH(p0 - HALF + n * D)];
#pragma unroll
        for (int m = 0; m < W; ++m) { a[m] = 0.f; bb[m] = 0.f; }
#pragma unroll
        for (int k = 0; k < 10; ++k)
#pragma unroll
            for (int m = 0; m < W; ++m) {
                float x = v[m + k];
                a[m] += x * f0[k]; bb[m] += x * f1[k];
            }
    }
    bar_lds();
    if (act) {
#pragma unroll
        for (int m = 0; m < W; ++m) {
            int p = p0 + m * D;
            out[PH(p)] = ((unsigned)(gbase + p) < (unsigned)T) ? a[m] : 0.f;
            in[PH(p)]  = bb[m];
        }
    }
    bar_lds();
}

__device__ __forceinline__ void k1_copyout(
    const float* __restrict__ buf, float* __restrict__ dst, int tid)
{
    for (int i4 = tid * 4; i4 < TS1; i4 += NT1 * 4) {
        int ph = PH(HB1 + i4);
        *(float4*)&dst[i4] = make_float4(buf[ph], buf[ph+1], buf[ph+2], buf[ph+3]);
    }
}

__global__ __launch_bounds__(256, 6) void udtcwt_k1(
    const float* __restrict__ x,
    const float* __restrict__ h0o, const float* __restrict__ h1o,
    const float* __restrict__ h0a, const float* __restrict__ h1a,
    const float* __restrict__ h0b, const float* __restrict__ h1b,
    float* __restrict__ out)
{
    __shared__ float A[SP1];
    __shared__ float Bf[SP1];

    const int tid   = threadIdx.x;
    const int bid   = blockIdx.x;
    const int tile  = bid & 31;
    const int chain = bid >> 5;
    const int shbit = chain & 1;
    const int cx    = (chain >> 1) & 7;
    const int b     = chain >> 4;
    const int c2    = shbit * 8 + cx;
    const int t0    = tile * TS1;
    const int gbase = t0 - HB1;          // %4 == 0

    const float* xin = x + (size_t)(b * 8 + cx) * T;
    for (int i4 = tid * 4; i4 < S1; i4 += NT1 * 4) {
        int gg = gbase + i4;
        float4 v = ((unsigned)gg < (unsigned)T)
                 ? *(const float4*)&xin[gg]
                 : make_float4(0.f, 0.f, 0.f, 0.f);
        int ph = PH(i4);
        A[ph] = v.x; A[ph+1] = v.y; A[ph+2] = v.z; A[ph+3] = v.w;
    }

    float f0[10], f1[10];
    {
        const float* F0 = (c2 & 1) ? h0b : h0a;
        const float* F1 = (c2 & 1) ? h1b : h1a;
#pragma unroll
        for (int k = 0; k < 10; ++k) { f0[k] = rfl(F0[k]); f1[k] = rfl(F1[k]); }
    }

    float* yh   = out + (size_t)B * 8 * T;
    const size_t LS = (size_t)B * C2 * T;
    float* psi0 = yh + (size_t)(b * C2 + c2) * T;

    bar_lds();
    if (shbit) k1_lvl1<1>(A, Bf, h0o, h1o, psi0, gbase, tid);
    else       k1_lvl1<0>(A, Bf, h0o, h1o, psi0, gbase, tid);
    bar_lds();

    k1_level<2, 9, 54>(Bf, A, f0, f1, gbase, tid);
    k1_copyout(Bf, psi0 + 1 * LS + t0, tid);
    k1_level<4, 9, 36>(A, Bf, f0, f1, gbase, tid);
    k1_copyout(A, psi0 + 2 * LS + t0, tid);
    k1_level<8, 9, 0>(Bf, A, f0, f1, gbase, tid);
    k1_copyout(Bf, psi0 + 3 * LS + t0, tid);
    k1_copyout(A, g_phi4 + (size_t)(b * C2 + c2) * T + t0, tid);
}

// ---------------- K2: levels 5-8, TS=8192, NT=768, in-place ----------------
static constexpr int NT2 = 768;
static constexpr int TS2 = 8192;
static constexpr int HB2 = 1080;
static constexpr int S2  = TS2 + 2 * HB2;    // 10352 floats = 41.4 KB

// In-place: all loads to regs before the barrier, stores after. Duplicate
// clamped chunks recompute identical values -> benign.
template <int D, int W, int MO, bool LAST>
__device__ __forceinline__ void k2_level(
    float* __restrict__ buf,
    const float (&f0)[10], const float (&f1)[10],
    float* __restrict__ psi_g, float* __restrict__ yl_g,
    int gbase, int tid, bool wr_yl)
{
    constexpr int HALF  = 9 * D / 2;
    constexpr int START = HB2 - MO;
    constexpr int N     = TS2 + 2 * MO;
    static_assert(N % D == 0, "");
    constexpr int NPD   = N / D;
    constexpr int CPC   = (NPD + W - 1) / W;
    constexpr int G     = D * CPC;
    static_assert(G <= NT2, "single chunk per thread required");
    constexpr int LOG2D = (D == 16 ? 4 : D == 32 ? 5 : D == 64 ? 6 : 7);

    float a[W], bb[W];
    int p0 = 0;
    const bool act = tid < G;
    const bool do_phi = !LAST || wr_yl;   // block-uniform
    if (act) {
        int r  = tid & (D - 1);
        int q  = tid >> LOG2D;
        int ms = q * W;
        if (ms > NPD - W) ms = NPD - W;
        p0 = START + r + ms * D;

        float v[W + 9];
#pragma unroll
        for (int n = 0; n < W + 9; ++n) v[n] = buf[p0 - HALF + n * D];
#pragma unroll
        for (int m = 0; m < W; ++m) { a[m] = 0.f; bb[m] = 0.f; }
        if (do_phi) {
#pragma unroll
            for (int k = 0; k < 10; ++k)
#pragma unroll
                for (int m = 0; m < W; ++m) {
                    float x = v[m + k];
                    a[m] += x * f0[k]; bb[m] += x * f1[k];
                }
        } else {
#pragma unroll
            for (int k = 0; k < 10; ++k)
#pragma unroll
                for (int m = 0; m < W; ++m) bb[m] += v[m + k] * f1[k];
        }
    }
    bar_lds();
    if (act) {
#pragma unroll
        for (int m = 0; m < W; ++m) {
            int p = p0 + m * D;
            const bool core = (unsigned)(p - HB2) < (unsigned)TS2;
            if (core) psi_g[gbase + p] = bb[m];
            if constexpr (!LAST) {
                buf[p] = ((unsigned)(gbase + p) < (unsigned)T) ? a[m] : 0.f;
            } else {
                if (wr_yl && core) yl_g[gbase + p] = a[m];
            }
        }
    }
    bar_lds();
}

__global__ __launch_bounds__(768, 6) void udtcwt_k2(
    const float* __restrict__ h0a, const float* __restrict__ h1a,
    const float* __restrict__ h0b, const float* __restrict__ h1b,
    float* __restrict__ out)
{
    __shared__ float A[S2];

    const int tid   = threadIdx.x;
    const int bid   = blockIdx.x;
    const int tile  = bid & 7;           // 8 tiles of 8192
    const int chain = bid >> 3;          // 0..63
    const int shbit = chain & 1;
    const int cx    = (chain >> 1) & 7;
    const int b     = chain >> 4;
    const int c2    = shbit * 8 + cx;
    const int gbase = tile * TS2 - HB2;  // %4 == 0

    const float* pin = g_phi4 + (size_t)(b * C2 + c2) * T;
    for (int i4 = tid * 4; i4 < S2; i4 += NT2 * 4) {
        int gg = gbase + i4;
        float4 v = ((unsigned)gg < (unsigned)T)
                 ? *(const float4*)&pin[gg]
                 : make_float4(0.f, 0.f, 0.f, 0.f);
        *(float4*)&A[i4] = v;
    }

    float f0[10], f1[10];
    {
        const float* F0 = (c2 & 1) ? h0b : h0a;
        const float* F1 = (c2 & 1) ? h1b : h1a;
#pragma unroll
        for (int k = 0; k < 10; ++k) { f0[k] = rfl(F0[k]); f1[k] = rfl(F1[k]); }
    }

    float* yl_g = out + (size_t)(b * 8 + c2) * T;    // used when c2<8
    float* yh   = out + (size_t)B * 8 * T;
    const size_t LS = (size_t)B * C2 * T;
    float* psi0 = yh + (size_t)(b * C2 + c2) * T;
    const bool wr_yl = (c2 < 8);

    bar_lds();
    k2_level< 16, 15, 1008, false>(A, f0, f1, psi0 + 4 * LS, nullptr, gbase, tid, false);
    k2_level< 32, 15,  864, false>(A, f0, f1, psi0 + 5 * LS, nullptr, gbase, tid, false);
    k2_level< 64, 15,  576, false>(A, f0, f1, psi0 + 6 * LS, nullptr, gbase, tid, false);
    k2_level<128, 15,    0, true >(A, f0, f1, psi0 + 7 * LS, yl_g,    gbase, tid, wr_yl);
}

extern "C" void kernel_launch(void* const* d_in, const int* in_sizes, int n_in,
                              void* d_out, int out_size, void* d_ws, size_t ws_size,
                              hipStream_t stream)
{
    const float* x   = (const float*)d_in[0];
    const float* h0o = (const float*)d_in[1];
    const float* h1o = (const float*)d_in[2];
    const float* h0a = (const float*)d_in[3];
    const float* h1a = (const float*)d_in[4];
    const float* h0b = (const float*)d_in[5];
    const float* h1b = (const float*)d_in[6];

    udtcwt_k1<<<64 * (T / TS1), NT1, 0, stream>>>(x, h0o, h1o, h0a, h1a, h0b, h1b,
                                                  (float*)d_out);
    udtcwt_k2<<<64 * (T / TS2), NT2, 0, stream>>>(h0a, h1a, h0b, h1b,
                                                  (float*)d_out);
}

// Round 13
// 47.147 us; speedup vs baseline: 1.1307x; 1.0388x over previous
//
#include <hip/hip_runtime.h>

// UDTCWT split cascade r13 = r12 + k1 vectorized-LDS (unpadded, b128) +
// TS1=4096 full-residency.
// K1: levels 1-4 (D=1,2,4,8), TS=4096, halo 68, UNPADDED double LDS, all
//     contiguous LDS ops as float4 (b128); psi transposed through dead LDS
//     buffer -> coalesced float4 global stores. LB(256,4): 33.9KB LDS ->
//     4 blocks/CU, grid 1024 exactly resident, zero tail.
// K2: levels 5-8 (D=16..128), TS=8192, NT=768, W=15, in-place LDS (r12).
// B=4, C=8 -> 16 chains, T=65536. Output: yl [4][8][T], yh [8][4][16][T].

static constexpr int B  = 4;
static constexpr int C2 = 16;
static constexpr int T  = 65536;

__device__ __forceinline__ float rfl(float x) {
    return __int_as_float(__builtin_amdgcn_readfirstlane(__float_as_int(x)));
}

// LDS-only barrier (measured neutral vs __syncthreads in r11; keeps global
// stores in flight).
__device__ __forceinline__ void bar_lds() {
    asm volatile("s_waitcnt lgkmcnt(0)" ::: "memory");
    __builtin_amdgcn_s_barrier();
}

__device__ float g_phi4[(size_t)B * C2 * T]; // 16.8 MB phi-after-lvl4

// ---------------- K1 ----------------
static constexpr int NT1 = 256;
static constexpr int TS1 = 4096;
static constexpr int HB1 = 68;
static constexpr int S1  = TS1 + 2 * HB1;    // 4232 floats, unpadded

template <int SH>
__device__ __forceinline__ void k1_lvl1(
    const float* __restrict__ in, float* __restrict__ out,
    const float* __restrict__ h0o, const float* __restrict__ h1o,
    float* __restrict__ psi_g, int gbase, int tid)
{
    float f0[5], f1[7];
#pragma unroll
    for (int k = 0; k < 5; ++k) f0[k] = rfl(h0o[k]);
#pragma unroll
    for (int k = 0; k < 7; ++k) f1[k] = rfl(h1o[k]);

    constexpr int OFF   = SH ? 1 : 2;      // w-array offset: w[k+OFF] = x[p4+WO+k]
    constexpr int FS    = SH ? 2 : 0;      // phi tap shift
    constexpr int MO    = 64;
    constexpr int START = HB1 - MO;        // 4
    constexpr int END   = HB1 + TS1 + MO;  // 4228

    for (int p4 = START + tid * 4; p4 < END; p4 += NT1 * 4) {
        // 12-float window [p4-4 .. p4+7] via 3 conflict-free b128 reads
        float w[12];
        {
            float4 w0 = *(const float4*)&in[p4 - 4];
            float4 w1 = *(const float4*)&in[p4];
            float4 w2 = *(const float4*)&in[p4 + 4];
            w[0]=w0.x; w[1]=w0.y; w[2]=w0.z; w[3]=w0.w;
            w[4]=w1.x; w[5]=w1.y; w[6]=w1.z; w[7]=w1.w;
            w[8]=w2.x; w[9]=w2.y; w[10]=w2.z; w[11]=w2.w;
        }
        // x[p4+WO+k] = w[k + 4 + WO]; WO = SH?-3:-2 -> w[k + OFF]
        float a[4];
#pragma unroll
        for (int i = 0; i < 4; ++i) {
            float s = 0.f;
#pragma unroll
            for (int k = 0; k < 5; ++k) s += w[i + k + FS + OFF] * f0[k];
            a[i] = s;
        }
        if ((unsigned)(p4 - HB1) < (unsigned)TS1) {
            float bb[4];
#pragma unroll
            for (int i = 0; i < 4; ++i) {
                float s = 0.f;
#pragma unroll
                for (int k = 0; k < 7; ++k) s += w[i + k + OFF] * f1[k];
                bb[i] = s;
            }
            *(float4*)&psi_g[gbase + p4] = make_float4(bb[0], bb[1], bb[2], bb[3]);
        }
        const bool inT = (unsigned)(gbase + p4) < (unsigned)T; // quad in or out
        *(float4*)&out[p4] = inT ? make_float4(a[0], a[1], a[2], a[3])
                                 : make_float4(0.f, 0.f, 0.f, 0.f);
    }
}

// compute | bar | {phi->out, psi->in(stage)} | bar.  G<=NT1 single chunk.
template <int D, int W, int MO>
__device__ __forceinline__ void k1_level(
    float* __restrict__ in, float* __restrict__ out,
    const float (&f0)[10], const float (&f1)[10],
    int gbase, int tid)
{
    constexpr int HALF  = 9 * D / 2;
    constexpr int START = HB1 - MO;
    constexpr int N     = TS1 + 2 * MO;
    static_assert(N % D == 0, "");
    constexpr int NPD   = N / D;
    constexpr int CPC   = (NPD + W - 1) / W;
    constexpr int G     = D * CPC;
    static_assert(G <= NT1, "single chunk per thread required");
    constexpr int LOG2D = (D == 2 ? 1 : D == 4 ? 2 : 3);

    float a[W], bb[W];
    int p0 = 0;
    const bool act = tid < G;
    if (act) {
        int r  = tid & (D - 1);
        int q  = tid >> LOG2D;
        int ms = q * W;
        if (ms > NPD - W) ms = NPD - W;   // clamp (dup work, benign)
        p0 = START + r + ms * D;

        float v[W + 9];
#pragma unroll
        for (int n = 0; n < W + 9; ++n) v[n] = in[p0 - HALF + n * D];
#pragma unroll
        for (int m = 0; m < W; ++m) { a[m] = 0.f; bb[m] = 0.f; }
#pragma unroll
        for (int k = 0; k < 10; ++k)
#pragma unroll
            for (int m = 0; m < W; ++m) {
                float x = v[m + k];
                a[m] += x * f0[k]; bb[m] += x * f1[k];
            }
    }
    bar_lds();
    if (act) {
#pragma unroll
        for (int m = 0; m < W; ++m) {
            int p = p0 + m * D;
            out[p] = ((unsigned)(gbase + p) < (unsigned)T) ? a[m] : 0.f;
            in[p]  = bb[m];
        }
    }
    bar_lds();
}

__device__ __forceinline__ void k1_copyout(
    const float* __restrict__ buf, float* __restrict__ dst, int tid)
{
    for (int i4 = tid * 4; i4 < TS1; i4 += NT1 * 4) {
        *(float4*)&dst[i4] = *(const float4*)&buf[HB1 + i4];  // HB1%4==0
    }
}

__global__ __launch_bounds__(256, 4) void udtcwt_k1(
    const float* __restrict__ x,
    const float* __restrict__ h0o, const float* __restrict__ h1o,
    const float* __restrict__ h0a, const float* __restrict__ h1a,
    const float* __restrict__ h0b, const float* __restrict__ h1b,
    float* __restrict__ out)
{
    __shared__ float A[S1];
    __shared__ float Bf[S1];

    const int tid   = threadIdx.x;
    const int bid   = blockIdx.x;
    const int tile  = bid & 15;          // 16 tiles of 4096
    const int chain = bid >> 4;          // 0..63
    const int shbit = chain & 1;
    const int cx    = (chain >> 1) & 7;
    const int b     = chain >> 4;
    const int c2    = shbit * 8 + cx;
    const int t0    = tile * TS1;
    const int gbase = t0 - HB1;          // %4 == 0

    const float* xin = x + (size_t)(b * 8 + cx) * T;
    for (int i4 = tid * 4; i4 < S1; i4 += NT1 * 4) {
        int gg = gbase + i4;             // quad fully in or out of [0,T)
        float4 v = ((unsigned)gg < (unsigned)T)
                 ? *(const float4*)&xin[gg]
                 : make_float4(0.f, 0.f, 0.f, 0.f);
        *(float4*)&A[i4] = v;
    }

    float f0[10], f1[10];
    {
        const float* F0 = (c2 & 1) ? h0b : h0a;
        const float* F1 = (c2 & 1) ? h1b : h1a;
#pragma unroll
        for (int k = 0; k < 10; ++k) { f0[k] = rfl(F0[k]); f1[k] = rfl(F1[k]); }
    }

    float* yh   = out + (size_t)B * 8 * T;
    const size_t LS = (size_t)B * C2 * T;
    float* psi0 = yh + (size_t)(b * C2 + c2) * T;

    bar_lds();
    if (shbit) k1_lvl1<1>(A, Bf, h0o, h1o, psi0, gbase, tid);
    else       k1_lvl1<0>(A, Bf, h0o, h1o, psi0, gbase, tid);
    bar_lds();

    k1_level<2, 17, 54>(Bf, A, f0, f1, gbase, tid);
    k1_copyout(Bf, psi0 + 1 * LS + t0, tid);
    k1_level<4, 17, 36>(A, Bf, f0, f1, gbase, tid);
    k1_copyout(A, psi0 + 2 * LS + t0, tid);
    k1_level<8, 17, 0>(Bf, A, f0, f1, gbase, tid);
    k1_copyout(Bf, psi0 + 3 * LS + t0, tid);
    k1_copyout(A, g_phi4 + (size_t)(b * C2 + c2) * T + t0, tid);
}

// ---------------- K2: levels 5-8, TS=8192, NT=768, in-place (r12) ----------------
static constexpr int NT2 = 768;
static constexpr int TS2 = 8192;
static constexpr int HB2 = 1080;
static constexpr int S2  = TS2 + 2 * HB2;    // 10352 floats = 41.4 KB

template <int D, int W, int MO, bool LAST>
__device__ __forceinline__ void k2_level(
    float* __restrict__ buf,
    const float (&f0)[10], const float (&f1)[10],
    float* __restrict__ psi_g, float* __restrict__ yl_g,
    int gbase, int tid, bool wr_yl)
{
    constexpr int HALF  = 9 * D / 2;
    constexpr int START = HB2 - MO;
    constexpr int N     = TS2 + 2 * MO;
    static_assert(N % D == 0, "");
    constexpr int NPD   = N / D;
    constexpr int CPC   = (NPD + W - 1) / W;
    constexpr int G     = D * CPC;
    static_assert(G <= NT2, "single chunk per thread required");
    constexpr int LOG2D = (D == 16 ? 4 : D == 32 ? 5 : D == 64 ? 6 : 7);

    float a[W], bb[W];
    int p0 = 0;
    const bool act = tid < G;
    const bool do_phi = !LAST || wr_yl;   // block-uniform
    if (act) {
        int r  = tid & (D - 1);
        int q  = tid >> LOG2D;
        int ms = q * W;
        if (ms > NPD - W) ms = NPD - W;
        p0 = START + r + ms * D;

        float v[W + 9];
#pragma unroll
        for (int n = 0; n < W + 9; ++n) v[n] = buf[p0 - HALF + n * D];
#pragma unroll
        for (int m = 0; m < W; ++m) { a[m] = 0.f; bb[m] = 0.f; }
        if (do_phi) {
#pragma unroll
            for (int k = 0; k < 10; ++k)
#pragma unroll
                for (int m = 0; m < W; ++m) {
                    float x = v[m + k];
                    a[m] += x * f0[k]; bb[m] += x * f1[k];
                }
        } else {
#pragma unroll
            for (int k = 0; k < 10; ++k)
#pragma unroll
                for (int m = 0; m < W; ++m) bb[m] += v[m + k] * f1[k];
        }
    }
    bar_lds();
    if (act) {
#pragma unroll
        for (int m = 0; m < W; ++m) {
            int p = p0 + m * D;
            const bool core = (unsigned)(p - HB2) < (unsigned)TS2;
            if (core) psi_g[gbase + p] = bb[m];
            if constexpr (!LAST) {
                buf[p] = ((unsigned)(gbase + p) < (unsigned)T) ? a[m] : 0.f;
            } else {
                if (wr_yl && core) yl_g[gbase + p] = a[m];
            }
        }
    }
    bar_lds();
}

__global__ __launch_bounds__(768, 6) void udtcwt_k2(
    const float* __restrict__ h0a, const float* __restrict__ h1a,
    const float* __restrict__ h0b, const float* __restrict__ h1b,
    float* __restrict__ out)
{
    __shared__ float A[S2];

    const int tid   = threadIdx.x;
    const int bid   = blockIdx.x;
    const int tile  = bid & 7;           // 8 tiles of 8192
    const int chain = bid >> 3;          // 0..63
    const int shbit = chain & 1;
    const int cx    = (chain >> 1) & 7;
    const int b     = chain >> 4;
    const int c2    = shbit * 8 + cx;
    const int gbase = tile * TS2 - HB2;  // %4 == 0

    const float* pin = g_phi4 + (size_t)(b * C2 + c2) * T;
    for (int i4 = tid * 4; i4 < S2; i4 += NT2 * 4) {
        int gg = gbase + i4;
        float4 v = ((unsigned)gg < (unsigned)T)
                 ? *(const float4*)&pin[gg]
                 : make_float4(0.f, 0.f, 0.f, 0.f);
        *(float4*)&A[i4] = v;
    }

    float f0[10], f1[10];
    {
        const float* F0 = (c2 & 1) ? h0b : h0a;
        const float* F1 = (c2 & 1) ? h1b : h1a;
#pragma unroll
        for (int k = 0; k < 10; ++k) { f0[k] = rfl(F0[k]); f1[k] = rfl(F1[k]); }
    }

    float* yl_g = out + (size_t)(b * 8 + c2) * T;    // used when c2<8
    float* yh   = out + (size_t)B * 8 * T;
    const size_t LS = (size_t)B * C2 * T;
    float* psi0 = yh + (size_t)(b * C2 + c2) * T;
    const bool wr_yl = (c2 < 8);

    bar_lds();
    k2_level< 16, 15, 1008, false>(A, f0, f1, psi0 + 4 * LS, nullptr, gbase, tid, false);
    k2_level< 32, 15,  864, false>(A, f0, f1, psi0 + 5 * LS, nullptr, gbase, tid, false);
    k2_level< 64, 15,  576, false>(A, f0, f1, psi0 + 6 * LS, nullptr, gbase, tid, false);
    k2_level<128, 15,    0, true >(A, f0, f1, psi0 + 7 * LS, yl_g,    gbase, tid, wr_yl);
}

extern "C" void kernel_launch(void* const* d_in, const int* in_sizes, int n_in,
                              void* d_out, int out_size, void* d_ws, size_t ws_size,
                              hipStream_t stream)
{
    const float* x   = (const float*)d_in[0];
    const float* h0o = (const float*)d_in[1];
    const float* h1o = (const float*)d_in[2];
    const float* h0a = (const float*)d_in[3];
    const float* h1a = (const float*)d_in[4];
    const float* h0b = (const float*)d_in[5];
    const float* h1b = (const float*)d_in[6];

    udtcwt_k1<<<64 * (T / TS1), NT1, 0, stream>>>(x, h0o, h1o, h0a, h1a, h0b, h1b,
                                                  (float*)d_out);
    udtcwt_k2<<<64 * (T / TS2), NT2, 0, stream>>>(h0a, h1a, h0b, h1b,
                                                  (float*)d_out);
}

// Round 14
// 43.876 us; speedup vs baseline: 1.2149x; 1.0745x over previous
//
#include <hip/hip_runtime.h>

// UDTCWT fully-fused r14: all 8 levels in ONE kernel, ONE in-place LDS
// buffer (compute|bar|store WAR-safe, proven r12) + 32KB psi-stage buffer
// for coalesced float4 psi output at D in {2,4,8} (transpose trick, r7).
// TS=8192, halo 1152, NT=768, LDS 74.75KB -> 2 blocks/CU, grid 512 exactly
// resident, zero tail. All contiguous LDS ops b128 (r13).
// B=4, C=8 -> 16 chains, T=65536. Output: yl [4][8][T], yh [8][4][16][T].

static constexpr int B  = 4;
static constexpr int C2 = 16;
static constexpr int T  = 65536;
static constexpr int NT = 768;
static constexpr int TS = 8192;
static constexpr int HB = 1152;
static constexpr int S  = TS + 2 * HB;   // 10496 floats = 41.98 KB

__device__ __forceinline__ float rfl(float x) {
    return __int_as_float(__builtin_amdgcn_readfirstlane(__float_as_int(x)));
}

// LDS-only barrier (measured neutral vs __syncthreads in r11).
__device__ __forceinline__ void bar_lds() {
    asm volatile("s_waitcnt lgkmcnt(0)" ::: "memory");
    __builtin_amdgcn_s_barrier();
}

// Margin chain: lvl1 out 1148; each dilated level consumes 4.5*D:
// 1136(D2) 1116(D4) 1080(D8) 1008(D16) 864(D32) 576(D64) 0(D128).

// ---------- Level 1 (D=1), in-place, 16 outputs (4 quads) per thread ----------
template <int SH>
__device__ __forceinline__ void f_lvl1(
    float* __restrict__ buf,
    const float* __restrict__ h0o, const float* __restrict__ h1o,
    float* __restrict__ psi_g, int gbase, int tid)
{
    float f0[5], f1[7];
#pragma unroll
    for (int k = 0; k < 5; ++k) f0[k] = rfl(h0o[k]);
#pragma unroll
    for (int k = 0; k < 7; ++k) f1[k] = rfl(h1o[k]);

    constexpr int OFF   = SH ? 1 : 2;       // w[i+k+OFF] = x[p0+i+WO+k]
    constexpr int FS    = SH ? 2 : 0;       // phi tap shift
    constexpr int MO    = 1148;
    constexpr int START = HB - MO;          // 4 (%4==0)
    constexpr int NQ    = (TS + 2 * MO) / 4;  // 2622 quads
    constexpr int G     = (NQ + 3) / 4;       // 656 threads
    const bool act = tid < G;

    int p0 = 0;
    float w[24], a[16], bb[16];
    if (act) {
        int qs = tid * 4;
        if (qs > NQ - 4) qs = NQ - 4;       // clamp (dup work, benign)
        p0 = START + qs * 4;
#pragma unroll
        for (int j = 0; j < 6; ++j)
            *(float4*)&w[4 * j] = *(const float4*)&buf[p0 - 4 + 4 * j];
#pragma unroll
        for (int i = 0; i < 16; ++i) {
            float sa = 0.f, sb = 0.f;
#pragma unroll
            for (int k = 0; k < 5; ++k) sa += w[i + k + FS + OFF] * f0[k];
#pragma unroll
            for (int k = 0; k < 7; ++k) sb += w[i + k + OFF] * f1[k];
            a[i] = sa; bb[i] = sb;
        }
    }
    bar_lds();
    if (act) {
#pragma unroll
        for (int qq = 0; qq < 4; ++qq) {
            int p = p0 + qq * 4;            // %4==0
            if ((unsigned)(p - HB) < (unsigned)TS)
                *(float4*)&psi_g[gbase + p] =
                    make_float4(bb[4*qq], bb[4*qq+1], bb[4*qq+2], bb[4*qq+3]);
            const bool inT = (unsigned)(gbase + p) < (unsigned)T;
            *(float4*)&buf[p] = inT
                ? make_float4(a[4*qq], a[4*qq+1], a[4*qq+2], a[4*qq+3])
                : make_float4(0.f, 0.f, 0.f, 0.f);
        }
    }
    bar_lds();
}

// ---------- Dilated level, in-place; STAGE -> psi via LDS stage buffer ----------
template <int D, int W, int MO, bool STAGE, bool LAST>
__device__ __forceinline__ void f_level(
    float* __restrict__ buf, float* __restrict__ psi_st,
    const float (&f0)[10], const float (&f1)[10],
    float* __restrict__ psi_g, float* __restrict__ yl_g,
    int gbase, int tid, bool wr_yl)
{
    constexpr int HALF  = 9 * D / 2;
    constexpr int START = HB - MO;
    constexpr int N     = TS + 2 * MO;
    static_assert(N % D == 0, "");
    constexpr int NPD   = N / D;
    constexpr int CPC   = (NPD + W - 1) / W;
    constexpr int G     = D * CPC;
    static_assert(G <= NT, "single chunk per thread required");
    constexpr int LOG2D = (D == 2 ? 1 : D == 4 ? 2 : D == 8 ? 3 :
                           D == 16 ? 4 : D == 32 ? 5 : D == 64 ? 6 : 7);

    float a[W], bb[W];
    int p0 = 0;
    const bool act = tid < G;
    const bool do_phi = !LAST || wr_yl;     // block-uniform
    if (act) {
        int r  = tid & (D - 1);
        int q  = tid >> LOG2D;
        int ms = q * W;
        if (ms > NPD - W) ms = NPD - W;     // clamp (dup work, benign)
        p0 = START + r + ms * D;

        float v[W + 9];
#pragma unroll
        for (int n = 0; n < W + 9; ++n) v[n] = buf[p0 - HALF + n * D];
#pragma unroll
        for (int m = 0; m < W; ++m) { a[m] = 0.f; bb[m] = 0.f; }
        if (do_phi) {
#pragma unroll
            for (int k = 0; k < 10; ++k)
#pragma unroll
                for (int m = 0; m < W; ++m) {
                    float x = v[m + k];
                    a[m] += x * f0[k]; bb[m] += x * f1[k];
                }
        } else {
#pragma unroll
            for (int k = 0; k < 10; ++k)
#pragma unroll
                for (int m = 0; m < W; ++m) bb[m] += v[m + k] * f1[k];
        }
    }
    bar_lds();
    if (act) {
#pragma unroll
        for (int m = 0; m < W; ++m) {
            int p = p0 + m * D;
            const bool core = (unsigned)(p - HB) < (unsigned)TS;
            if (core) {
                if constexpr (STAGE) psi_st[p - HB] = bb[m];
                else                 psi_g[gbase + p] = bb[m];
            }
            if constexpr (!LAST) {
                buf[p] = ((unsigned)(gbase + p) < (unsigned)T) ? a[m] : 0.f;
            } else {
                if (wr_yl && core) yl_g[gbase + p] = a[m];
            }
        }
    }
    bar_lds();
}

// Coalesced copy psi_st -> global (overlaps next level's compute phase).
__device__ __forceinline__ void f_copyout(
    const float* __restrict__ psi_st, float* __restrict__ dst, int tid)
{
    for (int i4 = tid * 4; i4 < TS; i4 += NT * 4)
        *(float4*)&dst[i4] = *(const float4*)&psi_st[i4];
}

__global__ __launch_bounds__(768, 6) void udtcwt_fused(
    const float* __restrict__ x,
    const float* __restrict__ h0o, const float* __restrict__ h1o,
    const float* __restrict__ h0a, const float* __restrict__ h1a,
    const float* __restrict__ h0b, const float* __restrict__ h1b,
    float* __restrict__ out)
{
    __shared__ float A[S];       // 41.98 KB, in-place phi chain
    __shared__ float P[TS];      // 32 KB psi stage

    const int tid   = threadIdx.x;
    const int bid   = blockIdx.x;
    const int tile  = bid & 7;           // 8 tiles of 8192
    const int chain = bid >> 3;          // 0..63
    const int shbit = chain & 1;
    const int cx    = (chain >> 1) & 7;
    const int b     = chain >> 4;
    const int c2    = shbit * 8 + cx;
    const int t0    = tile * TS;
    const int gbase = t0 - HB;           // %4 == 0

    // stage x tile + halo (zeros outside [0,T)); all b128
    const float* xin = x + (size_t)(b * 8 + cx) * T;
    for (int i4 = tid * 4; i4 < S; i4 += NT * 4) {
        int gg = gbase + i4;             // quad fully in or out of [0,T)
        float4 v = ((unsigned)gg < (unsigned)T)
                 ? *(const float4*)&xin[gg]
                 : make_float4(0.f, 0.f, 0.f, 0.f);
        *(float4*)&A[i4] = v;
    }

    float f0[10], f1[10];
    {
        const float* F0 = (c2 & 1) ? h0b : h0a;
        const float* F1 = (c2 & 1) ? h1b : h1a;
#pragma unroll
        for (int k = 0; k < 10; ++k) { f0[k] = rfl(F0[k]); f1[k] = rfl(F1[k]); }
    }

    float* yl_g = out + (size_t)(b * 8 + c2) * T;    // used when c2<8
    float* yh   = out + (size_t)B * 8 * T;
    const size_t LS = (size_t)B * C2 * T;
    float* psi0 = yh + (size_t)(b * C2 + c2) * T;
    const bool wr_yl = (c2 < 8);

    bar_lds();
    if (shbit) f_lvl1<1>(A, h0o, h1o, psi0, gbase, tid);
    else       f_lvl1<0>(A, h0o, h1o, psi0, gbase, tid);

    f_level<  2, 15, 1136, true,  false>(A, P, f0, f1, nullptr, nullptr, gbase, tid, false);
    f_copyout(P, psi0 + 1 * LS + t0, tid);
    f_level<  4, 15, 1116, true,  false>(A, P, f0, f1, nullptr, nullptr, gbase, tid, false);
    f_copyout(P, psi0 + 2 * LS + t0, tid);
    f_level<  8, 15, 1080, true,  false>(A, P, f0, f1, nullptr, nullptr, gbase, tid, false);
    f_copyout(P, psi0 + 3 * LS + t0, tid);
    f_level< 16, 15, 1008, false, false>(A, P, f0, f1, psi0 + 4 * LS, nullptr, gbase, tid, false);
    f_level< 32, 15,  864, false, false>(A, P, f0, f1, psi0 + 5 * LS, nullptr, gbase, tid, false);
    f_level< 64, 15,  576, false, false>(A, P, f0, f1, psi0 + 6 * LS, nullptr, gbase, tid, false);
    f_level<128, 15,    0, false, true >(A, P, f0, f1, psi0 + 7 * LS, yl_g,    gbase, tid, wr_yl);
}

extern "C" void kernel_launch(void* const* d_in, const int* in_sizes, int n_in,
                              void* d_out, int out_size, void* d_ws, size_t ws_size,
                              hipStream_t stream)
{
    const float* x   = (const float*)d_in[0];
    const float* h0o = (const float*)d_in[1];
    const float* h1o = (const float*)d_in[2];
    const float* h0a = (const float*)d_in[3];
    const float* h1a = (const float*)d_in[4];
    const float* h0b = (const float*)d_in[5];
    const float* h1b = (const float*)d_in[6];

    const int nblocks = 64 * (T / TS);   // 512
    udtcwt_fused<<<nblocks, NT, 0, stream>>>(x, h0o, h1o, h0a, h1a, h0b, h1b,
                                             (float*)d_out);
}